// Round 5
// baseline (378.508 us; speedup 1.0000x reference)
//
#include <hip/hip_runtime.h>
#include <math.h>

#define PI_F 3.14159265358979323846f
#define BSTRIDE 404   // basis row stride (400 taps + 4 zero pad)

// ---------------------------------------------------------------------------
// Prep: softmax over sub-axis (also to d_out), scaled-transposed CsT copies
// (zero-padded to 2048 / 256 rows), and the 24x404 masked cos-basis table.
// ---------------------------------------------------------------------------
__global__ __launch_bounds__(256) void prep_kernel(
    const float* __restrict__ Ce_raw, const float* __restrict__ Ci_raw,
    const float* __restrict__ Escale, const float* __restrict__ Iscale,
    const float* __restrict__ temp,
    float* __restrict__ CsT_e, float* __restrict__ CsT_i,
    float* __restrict__ basis,
    float* __restrict__ outCe, float* __restrict__ outCi)
{
    int id = blockIdx.x * 256 + threadIdx.x;
    if (id < 2000) {
        int e = id;
        float t = temp[0];
        float v[20];
        float m = -1e30f;
        #pragma unroll
        for (int s = 0; s < 20; ++s) { v[s] = Ce_raw[s * 2000 + e] / t; m = fmaxf(m, v[s]); }
        float sum = 0.f;
        #pragma unroll
        for (int s = 0; s < 20; ++s) { v[s] = expf(v[s] - m); sum += v[s]; }
        float inv = 1.f / sum;
        float sc = expf(Escale[e]);
        #pragma unroll
        for (int s = 0; s < 20; ++s) {
            float p = v[s] * inv;
            outCe[s * 2000 + e] = p;
            CsT_e[e * 20 + s] = p * sc;
        }
    } else if (id < 2200) {
        int e = id - 2000;
        float t = temp[0];
        float v[20];
        float m = -1e30f;
        #pragma unroll
        for (int s = 0; s < 20; ++s) { v[s] = Ci_raw[s * 200 + e] / t; m = fmaxf(m, v[s]); }
        float sum = 0.f;
        #pragma unroll
        for (int s = 0; s < 20; ++s) { v[s] = expf(v[s] - m); sum += v[s]; }
        float inv = 1.f / sum;
        float sc = expf(Iscale[e]);
        #pragma unroll
        for (int s = 0; s < 20; ++s) {
            float p = v[s] * inv;
            outCi[s * 200 + e] = p;
            CsT_i[e * 20 + s] = p * sc;
        }
    } else if (id < 2200 + 24 * BSTRIDE) {
        int idx = id - 2200;
        int j = idx / BSTRIDE, d = idx - j * BSTRIDE;
        float val = 0.f;
        if (d < 400) {
            float raw = 6.0f * logf((float)d + 1.0f + 1e-7f);
            float ph = (PI_F * 0.5f) * (float)j;
            if (raw >= ph - PI_F && raw <= ph + PI_F) val = 0.5f * cosf(raw - ph) + 0.5f;
        }
        basis[idx] = val;
    } else if (id < 11896 + 48) {               // CsT_e pad rows 2000..2047
        int row = 2000 + (id - 11896);
        #pragma unroll
        for (int s = 0; s < 20; ++s) CsT_e[row * 20 + s] = 0.f;
    } else if (id < 11944 + 56) {               // CsT_i pad rows 200..255
        int row = 200 + (id - 11944);
        #pragma unroll
        for (int s = 0; s < 20; ++s) CsT_i[row * 20 + s] = 0.f;
    }
}

// ---------------------------------------------------------------------------
// syn einsum, double-buffered LDS: per 128-e chunk, issue next chunk's
// coalesced float4 loads -> barrier -> compute current from LDS -> write
// staged regs into the other buffer (T14 split: HBM latency hides under FMAs).
// ---------------------------------------------------------------------------
template <int NCHUNK>
__global__ __launch_bounds__(256) void syn_kernel(
    const float* __restrict__ S, const float* __restrict__ CsT,
    float* __restrict__ syn, int Eno)
{
    __shared__ float4 tile[2][64 * 33];                    // 2 x 33792 B
    float* red = reinterpret_cast<float*>(tile);           // [64][4][20] alias
    const int tid = threadIdx.x;
    const int lane = tid & 63;
    const int w = __builtin_amdgcn_readfirstlane(tid >> 6);
    const int r0 = blockIdx.x * 64;

    float acc[20];
    #pragma unroll
    for (int s = 0; s < 20; ++s) acc[s] = 0.f;

    float4 st[8];
    // issue chunk ch's loads into regs
    auto issue = [&](int ch, float4 (&v)[8]) {
        const int ebase = ch * 128;
        #pragma unroll
        for (int i = 0; i < 8; ++i) {
            int f = tid + i * 256;
            int row = f >> 5, col4 = f & 31;
            int e0 = ebase + col4 * 4;
            v[i] = make_float4(0.f, 0.f, 0.f, 0.f);
            if (e0 + 4 <= Eno)
                v[i] = *reinterpret_cast<const float4*>(S + (size_t)(r0 + row) * Eno + e0);
        }
    };
    auto put = [&](int buf, float4 (&v)[8]) {
        #pragma unroll
        for (int i = 0; i < 8; ++i) {
            int f = tid + i * 256;
            int row = f >> 5, col4 = f & 31;
            tile[buf][row * 33 + col4] = v[i];
        }
    };

    issue(0, st);
    put(0, st);
    int cur = 0;

    for (int ch = 0; ch < NCHUNK; ++ch) {
        float4 nx[8];
        if (ch + 1 < NCHUNK) issue(ch + 1, nx);   // loads in flight over compute
        __syncthreads();                          // tile[cur] ready

        const int ebase = ch * 128;
        const float4* crow = reinterpret_cast<const float4*>(CsT + (size_t)(ebase + w * 32) * 20);
        const float4* tl = tile[cur];
        #pragma unroll
        for (int c4 = 0; c4 < 8; ++c4) {
            float4 v = tl[lane * 33 + w * 8 + c4];
            const float4* ct = crow + c4 * 20;             // 4 e-rows x 5 float4
            float vv[4] = {v.x, v.y, v.z, v.w};
            #pragma unroll
            for (int q = 0; q < 4; ++q) {
                float sv = vv[q];
                #pragma unroll
                for (int c5 = 0; c5 < 5; ++c5) {
                    float4 cc = ct[q * 5 + c5];
                    acc[c5 * 4 + 0] = fmaf(sv, cc.x, acc[c5 * 4 + 0]);
                    acc[c5 * 4 + 1] = fmaf(sv, cc.y, acc[c5 * 4 + 1]);
                    acc[c5 * 4 + 2] = fmaf(sv, cc.z, acc[c5 * 4 + 2]);
                    acc[c5 * 4 + 3] = fmaf(sv, cc.w, acc[c5 * 4 + 3]);
                }
            }
        }
        if (ch + 1 < NCHUNK) put(cur ^ 1, nx);    // other buffer: no race; next
        cur ^= 1;                                 // barrier orders write->read
    }
    __syncthreads();

    #pragma unroll
    for (int s = 0; s < 20; ++s) red[(lane * 4 + w) * 20 + s] = acc[s];
    __syncthreads();

    #pragma unroll
    for (int i = 0; i < 5; ++i) {                          // p = s*64 + row
        int p = tid + i * 256;
        int row = p & 63, s = p >> 6;
        float a = red[(row * 4 + 0) * 20 + s] + red[(row * 4 + 1) * 20 + s]
                + red[(row * 4 + 2) * 20 + s] + red[(row * 4 + 3) * 20 + s];
        int r = r0 + row;
        int b = r / 5000, t = r - b * 5000;
        syn[((size_t)b * 20 + s) * 5000 + t] = a;          // coalesced per s
    }
}

// ---------------------------------------------------------------------------
// Fused basis-conv + layer1(tanh) + layer2 reduce.
// Bit-rotate LDS swizzle: phys4(g) = (g&~15)|((g>>1)&7)|((g&1)<<3) -> stride-2
// fixed-parity b128 reads conflict-free; phys4(g+1)=phys4(g)+8.
// Unroll-8 two-bank software pipeline: every LDS pair load and basis-coef
// s_load issued 3 bodies (~190 cyc) before first use; zero rotation movs.
// 16-granule LDS guard band absorbs benign pipeline overshoot (never used).
// ---------------------------------------------------------------------------
__device__ const int CJ_LO[24] = {0,0,0,0,0,0,0,0,0,4,4,8,12,16,20,28,36,48,64,84,108,140,184,240};
__device__ const int CJ_NB[24] = {1,1,1,1,2,2,3,3,4,4,5,6,7,9,12,15,19,25,31,41,53,65,54,40};

__device__ __forceinline__ int phys4(int g) {
    return (g & ~15) | ((g >> 1) & 7) | ((g & 1) << 3);
}

__global__ __launch_bounds__(128) void conv_kernel(
    const float* __restrict__ syn_e, const float* __restrict__ syn_i,
    const float* __restrict__ basis,
    const float* __restrict__ W_e, const float* __restrict__ W_i,
    const float* __restrict__ b1, const float* __restrict__ W2,
    float* __restrict__ sub_out)
{
    __shared__ float4 win4[16 + 464];             // 16-granule guard + window
    float4* wbase = win4 + 16;
    float2* win2 = reinterpret_cast<float2*>(wbase);
    const int tid = threadIdx.x;
    const int tile = blockIdx.x, s = blockIdx.y, bz = blockIdx.z;
    const int t0 = tile * 512;

    const float* se = syn_e + ((size_t)bz * 20 + s) * 5000;
    const float* si = syn_i + ((size_t)bz * 20 + s) * 5000;
    for (int l = tid; l < 920; l += 128) {
        int t = t0 - 404 + l;
        float ve = 0.f, vi = 0.f;
        if ((unsigned)t < 5000u) { ve = se[t]; vi = si[t]; }
        int g = l >> 1;
        win2[2 * phys4(g) + (l & 1)] = make_float2(ve, vi);
    }
    __syncthreads();

    float z[16][4];
    #pragma unroll
    for (int h = 0; h < 16; ++h) {
        float bv = b1[s * 16 + h];
        #pragma unroll
        for (int k = 0; k < 4; ++k) z[h][k] = bv;
    }

    const int base = 4 * tid + 400;

    for (int j = 0; j < 24; ++j) {
        const float4* bj4 = reinterpret_cast<const float4*>(basis + j * BSTRIDE);
        const int lo = CJ_LO[j];
        const int nb = CJ_NB[j];
        const int co = lo >> 2;
        float be0 = 0.f, be1 = 0.f, be2 = 0.f, be3 = 0.f;
        float bi0 = 0.f, bi1 = 0.f, bi2 = 0.f, bi3 = 0.f;

        // body for tap-block n: V0V1 = Pair(n) (granules g0-2n, +1),
        // V2V3 = Pair(n-1); coefs c = basis[lo+4n .. +3]
        auto body = [&](const float4& V0, const float4& V1,
                        const float4& V2, const float4& V3, const float4& c) {
            be0 = fmaf(c.x, V2.x, be0); bi0 = fmaf(c.x, V2.y, bi0);
            be1 = fmaf(c.x, V2.z, be1); bi1 = fmaf(c.x, V2.w, bi1);
            be2 = fmaf(c.x, V3.x, be2); bi2 = fmaf(c.x, V3.y, bi2);
            be3 = fmaf(c.x, V3.z, be3); bi3 = fmaf(c.x, V3.w, bi3);
            be0 = fmaf(c.y, V1.z, be0); bi0 = fmaf(c.y, V1.w, bi0);
            be1 = fmaf(c.y, V2.x, be1); bi1 = fmaf(c.y, V2.y, bi1);
            be2 = fmaf(c.y, V2.z, be2); bi2 = fmaf(c.y, V2.w, bi2);
            be3 = fmaf(c.y, V3.x, be3); bi3 = fmaf(c.y, V3.y, bi3);
            be0 = fmaf(c.z, V1.x, be0); bi0 = fmaf(c.z, V1.y, bi0);
            be1 = fmaf(c.z, V1.z, be1); bi1 = fmaf(c.z, V1.w, bi1);
            be2 = fmaf(c.z, V2.x, be2); bi2 = fmaf(c.z, V2.y, bi2);
            be3 = fmaf(c.z, V2.z, be3); bi3 = fmaf(c.z, V2.w, bi3);
            be0 = fmaf(c.w, V0.z, be0); bi0 = fmaf(c.w, V0.w, bi0);
            be1 = fmaf(c.w, V1.x, be1); bi1 = fmaf(c.w, V1.y, bi1);
            be2 = fmaf(c.w, V1.z, be2); bi2 = fmaf(c.w, V1.w, bi2);
            be3 = fmaf(c.w, V2.x, be3); bi3 = fmaf(c.w, V2.y, bi3);
        };

        const int g0 = (base - lo) >> 1;          // even
        auto LP = [&](int n, float4& lo4, float4& hi4) {
            int p = phys4(g0 - 2 * n);
            lo4 = wbase[p]; hi4 = wbase[p + 8];
        };

        float4 A0, A1, B0, B1, C0, C1, D0, D1;
        float4 E0, E1, F0, F1, G0, G1, H0, H1;
        LP(-1, A0, A1); LP(0, B0, B1); LP(1, C0, C1); LP(2, D0, D1);
        float4 cB = bj4[co], cC = bj4[co + 1], cD = bj4[co + 2];

        int bb = 0;
        while (bb + 8 <= nb) {
            // bank A..D current, load E..H (pairs bb+3..bb+6, 3-body lookahead)
            LP(bb + 3, E0, E1); float4 cE = bj4[co + bb + 3];
            body(B0, B1, A0, A1, cB);
            LP(bb + 4, F0, F1); float4 cF = bj4[co + bb + 4];
            body(C0, C1, B0, B1, cC);
            LP(bb + 5, G0, G1); float4 cG = bj4[co + bb + 5];
            body(D0, D1, C0, C1, cD);
            LP(bb + 6, H0, H1); float4 cH = bj4[co + bb + 6];
            body(E0, E1, D0, D1, cE);
            // bank E..H current, refill A..D (pairs bb+7..bb+10)
            LP(bb + 7, A0, A1); float4 cI = bj4[co + bb + 7];
            body(F0, F1, E0, E1, cF);
            LP(bb + 8, B0, B1); cB = bj4[co + bb + 8];
            body(G0, G1, F0, F1, cG);
            LP(bb + 9, C0, C1); cC = bj4[co + bb + 9];
            body(H0, H1, G0, G1, cH);
            LP(bb + 10, D0, D1); cD = bj4[co + bb + 10];
            body(A0, A1, H0, H1, cI);
            bb += 8;
        }
        // invariant: A=P(bb-1), B=P(bb), C=P(bb+1), D=P(bb+2); cB..cD = c(bb..bb+2)
        int r = nb - bb;
        if (r > 0) { body(B0, B1, A0, A1, cB);
          if (r > 1) { body(C0, C1, B0, B1, cC);
            if (r > 2) { body(D0, D1, C0, C1, cD);
              if (r > 3) { LP(bb + 3, E0, E1); float4 cE = bj4[co + bb + 3];
                body(E0, E1, D0, D1, cE);
                if (r > 4) { LP(bb + 4, F0, F1); float4 cF = bj4[co + bb + 4];
                  body(F0, F1, E0, E1, cF);
                  if (r > 5) { LP(bb + 5, G0, G1); float4 cG = bj4[co + bb + 5];
                    body(G0, G1, F0, F1, cG);
                    if (r > 6) { LP(bb + 6, H0, H1); float4 cH = bj4[co + bb + 6];
                      body(H0, H1, G0, G1, cH); } } } } } } }

        #pragma unroll
        for (int h = 0; h < 16; ++h) {
            float we = W_e[(s * 16 + h) * 24 + j];
            float wi = W_i[(s * 16 + h) * 24 + j];
            z[h][0] = fmaf(we, be0, fmaf(wi, bi0, z[h][0]));
            z[h][1] = fmaf(we, be1, fmaf(wi, bi1, z[h][1]));
            z[h][2] = fmaf(we, be2, fmaf(wi, bi2, z[h][2]));
            z[h][3] = fmaf(we, be3, fmaf(wi, bi3, z[h][3]));
        }
    }

    float w2v[16];
    #pragma unroll
    for (int h = 0; h < 16; ++h) w2v[h] = __expf(W2[s * 16 + h]);

    #pragma unroll
    for (int k = 0; k < 4; ++k) {
        int t = t0 + 4 * tid + k;
        if (t < 5000) {
            float acc = 0.f;
            #pragma unroll
            for (int h = 0; h < 16; ++h) {
                float e2 = __expf(2.0f * z[h][k]);
                float th = 1.0f - 2.0f / (e2 + 1.0f);
                acc = fmaf(w2v[h], th, acc);
            }
            sub_out[((size_t)bz * 5000 + t) * 20 + s] = acc;
        }
    }
}

// ---------------------------------------------------------------------------
// final[b,t] = V_o + sum_s sub_out[b,t,s]
// ---------------------------------------------------------------------------
__global__ __launch_bounds__(256) void final_kernel(
    const float* __restrict__ sub_out, const float* __restrict__ V_o,
    float* __restrict__ fin)
{
    int r = blockIdx.x * 256 + threadIdx.x;
    if (r < 40000) {
        const float* p = sub_out + (size_t)r * 20;
        float a = V_o[0];
        #pragma unroll
        for (int s = 0; s < 20; ++s) a += p[s];
        fin[r] = a;
    }
}

extern "C" void kernel_launch(void* const* d_in, const int* in_sizes, int n_in,
                              void* d_out, int out_size, void* d_ws, size_t ws_size,
                              hipStream_t stream)
{
    const float* S_e     = (const float*)d_in[0];
    const float* S_i     = (const float*)d_in[1];
    const float* E_scale = (const float*)d_in[2];
    const float* I_scale = (const float*)d_in[3];
    const float* W_e     = (const float*)d_in[4];
    const float* W_i     = (const float*)d_in[5];
    const float* W2      = (const float*)d_in[6];
    const float* b1      = (const float*)d_in[7];
    const float* Ce_raw  = (const float*)d_in[8];
    const float* Ci_raw  = (const float*)d_in[9];
    const float* V_o     = (const float*)d_in[10];
    const float* temp    = (const float*)d_in[11];

    float* out     = (float*)d_out;
    float* fin     = out;              // 40000
    float* sub_out = out + 40000;      // 800000
    float* outCe   = out + 840000;     // 40000
    float* outCi   = out + 880000;     // 4000

    float* ws    = (float*)d_ws;
    float* CsT_e = ws;                 // 2048*20 = 40960 (zero-padded)
    float* CsT_i = ws + 40960;         // 256*20  = 5120  (zero-padded)
    float* basis = ws + 46080;         // 24*404  = 9696
    float* syn_e = ws + 55776;         // 800000
    float* syn_i = ws + 855776;        // 800000

    prep_kernel<<<47, 256, 0, stream>>>(Ce_raw, Ci_raw, E_scale, I_scale, temp,
                                        CsT_e, CsT_i, basis, outCe, outCi);
    syn_kernel<16><<<625, 256, 0, stream>>>(S_e, CsT_e, syn_e, 2000);
    syn_kernel<2><<<625, 256, 0, stream>>>(S_i, CsT_i, syn_i, 200);
    conv_kernel<<<dim3(10, 20, 8), 128, 0, stream>>>(syn_e, syn_i, basis,
                                                     W_e, W_i, b1, W2, sub_out);
    final_kernel<<<157, 256, 0, stream>>>(sub_out, V_o, fin);
}

// Round 6
// 292.627 us; speedup vs baseline: 1.2935x; 1.2935x over previous
//
#include <hip/hip_runtime.h>
#include <math.h>

#define PI_F 3.14159265358979323846f
#define BSTRIDE 404   // basis row stride (400 taps + 4 zero pad)

// ---------------------------------------------------------------------------
// Prep: softmax over sub-axis (also to d_out), scaled-transposed CsT copies
// (zero-padded to 2048 / 256 rows), and the 24x404 masked cos-basis table.
// ---------------------------------------------------------------------------
__global__ __launch_bounds__(256) void prep_kernel(
    const float* __restrict__ Ce_raw, const float* __restrict__ Ci_raw,
    const float* __restrict__ Escale, const float* __restrict__ Iscale,
    const float* __restrict__ temp,
    float* __restrict__ CsT_e, float* __restrict__ CsT_i,
    float* __restrict__ basis,
    float* __restrict__ outCe, float* __restrict__ outCi)
{
    int id = blockIdx.x * 256 + threadIdx.x;
    if (id < 2000) {
        int e = id;
        float t = temp[0];
        float v[20];
        float m = -1e30f;
        #pragma unroll
        for (int s = 0; s < 20; ++s) { v[s] = Ce_raw[s * 2000 + e] / t; m = fmaxf(m, v[s]); }
        float sum = 0.f;
        #pragma unroll
        for (int s = 0; s < 20; ++s) { v[s] = expf(v[s] - m); sum += v[s]; }
        float inv = 1.f / sum;
        float sc = expf(Escale[e]);
        #pragma unroll
        for (int s = 0; s < 20; ++s) {
            float p = v[s] * inv;
            outCe[s * 2000 + e] = p;
            CsT_e[e * 20 + s] = p * sc;
        }
    } else if (id < 2200) {
        int e = id - 2000;
        float t = temp[0];
        float v[20];
        float m = -1e30f;
        #pragma unroll
        for (int s = 0; s < 20; ++s) { v[s] = Ci_raw[s * 200 + e] / t; m = fmaxf(m, v[s]); }
        float sum = 0.f;
        #pragma unroll
        for (int s = 0; s < 20; ++s) { v[s] = expf(v[s] - m); sum += v[s]; }
        float inv = 1.f / sum;
        float sc = expf(Iscale[e]);
        #pragma unroll
        for (int s = 0; s < 20; ++s) {
            float p = v[s] * inv;
            outCi[s * 200 + e] = p;
            CsT_i[e * 20 + s] = p * sc;
        }
    } else if (id < 2200 + 24 * BSTRIDE) {
        int idx = id - 2200;
        int j = idx / BSTRIDE, d = idx - j * BSTRIDE;
        float val = 0.f;
        if (d < 400) {
            float raw = 6.0f * logf((float)d + 1.0f + 1e-7f);
            float ph = (PI_F * 0.5f) * (float)j;
            if (raw >= ph - PI_F && raw <= ph + PI_F) val = 0.5f * cosf(raw - ph) + 0.5f;
        }
        basis[idx] = val;
    } else if (id < 11896 + 48) {               // CsT_e pad rows 2000..2047
        int row = 2000 + (id - 11896);
        #pragma unroll
        for (int s = 0; s < 20; ++s) CsT_e[row * 20 + s] = 0.f;
    } else if (id < 11944 + 56) {               // CsT_i pad rows 200..255
        int row = 200 + (id - 11944);
        #pragma unroll
        for (int s = 0; s < 20; ++s) CsT_i[row * 20 + s] = 0.f;
    }
}

// ---------------------------------------------------------------------------
// syn einsum: single 33.8KB LDS tile (4 blocks/CU), register-staged prefetch
// (issue next chunk's 8 coalesced float4 loads, compute current, barrier,
// vmcnt(0)+ds_write, barrier). red[4][64][21]: lane-stride 21 floats is
// coprime with 32 banks -> conflict-free partial reduce (round-3's stride-80
// layout was a 32-way conflict, SQ_LDS_BANK_CONFLICT=1.8e6).
// ---------------------------------------------------------------------------
template <int NCHUNK>
__global__ __launch_bounds__(256) void syn_kernel(
    const float* __restrict__ S, const float* __restrict__ CsT,
    float* __restrict__ syn, int Eno)
{
    __shared__ float4 tile[64 * 33];                       // 33792 B
    float* red = reinterpret_cast<float*>(tile);           // [4][64][21] alias
    const int tid = threadIdx.x;
    const int lane = tid & 63;
    const int w = __builtin_amdgcn_readfirstlane(tid >> 6);
    const int r0 = blockIdx.x * 64;

    float acc[20];
    #pragma unroll
    for (int s = 0; s < 20; ++s) acc[s] = 0.f;

    const int frow = tid >> 5, fcol = tid & 31;            // staging coords

    auto issue = [&](int ch, float4 (&v)[8]) {
        const int ebase = ch * 128;
        #pragma unroll
        for (int i = 0; i < 8; ++i) {
            int row = frow + i * 8;
            int e0 = ebase + fcol * 4;
            v[i] = make_float4(0.f, 0.f, 0.f, 0.f);
            if (e0 + 4 <= Eno)
                v[i] = *reinterpret_cast<const float4*>(S + (size_t)(r0 + row) * Eno + e0);
        }
    };
    auto put = [&](float4 (&v)[8]) {
        #pragma unroll
        for (int i = 0; i < 8; ++i)
            tile[(frow + i * 8) * 33 + fcol] = v[i];
    };

    float4 nx[8];
    issue(0, nx);
    put(nx);                                   // vmcnt(0) then ds_write

    for (int ch = 0; ch < NCHUNK; ++ch) {
        __syncthreads();                       // tile ready for reading
        if (ch + 1 < NCHUNK) issue(ch + 1, nx);  // loads fly under compute

        const int ebase = ch * 128;
        const float4* crow = reinterpret_cast<const float4*>(CsT + (size_t)(ebase + w * 32) * 20);
        #pragma unroll
        for (int c4 = 0; c4 < 8; ++c4) {
            float4 v = tile[lane * 33 + w * 8 + c4];
            const float4* ct = crow + c4 * 20;             // 4 e-rows x 5 float4
            float vv[4] = {v.x, v.y, v.z, v.w};
            #pragma unroll
            for (int q = 0; q < 4; ++q) {
                float sv = vv[q];
                #pragma unroll
                for (int c5 = 0; c5 < 5; ++c5) {
                    float4 cc = ct[q * 5 + c5];
                    acc[c5 * 4 + 0] = fmaf(sv, cc.x, acc[c5 * 4 + 0]);
                    acc[c5 * 4 + 1] = fmaf(sv, cc.y, acc[c5 * 4 + 1]);
                    acc[c5 * 4 + 2] = fmaf(sv, cc.z, acc[c5 * 4 + 2]);
                    acc[c5 * 4 + 3] = fmaf(sv, cc.w, acc[c5 * 4 + 3]);
                }
            }
        }
        __syncthreads();                       // all reads done
        if (ch + 1 < NCHUNK) put(nx);          // write next chunk
    }

    #pragma unroll
    for (int s = 0; s < 20; ++s) red[(w * 64 + lane) * 21 + s] = acc[s];
    __syncthreads();

    #pragma unroll
    for (int i = 0; i < 5; ++i) {                          // p = s*64 + row
        int p = tid + i * 256;
        int row = p & 63, s = p >> 6;
        float a = red[(0 * 64 + row) * 21 + s] + red[(1 * 64 + row) * 21 + s]
                + red[(2 * 64 + row) * 21 + s] + red[(3 * 64 + row) * 21 + s];
        int r = r0 + row;
        int b = r / 5000, t = r - b * 5000;
        syn[((size_t)b * 20 + s) * 5000 + t] = a;          // coalesced per s
    }
}

// ---------------------------------------------------------------------------
// Fused basis-conv + layer1(tanh) + layer2 reduce.
// Bit-rotate LDS swizzle: phys4(g) = (g&~15)|((g>>1)&7)|((g&1)<<3) -> stride-2
// fixed-parity b128 reads conflict-free; phys4(g+1)=phys4(g)+8.
// Unroll-8 two-bank software pipeline: every LDS pair load and basis-coef
// load issued 3 bodies (~190 cyc) before first use; zero rotation movs.
// 16-granule LDS guard band absorbs benign pipeline overshoot (never used).
// ---------------------------------------------------------------------------
__device__ const int CJ_LO[24] = {0,0,0,0,0,0,0,0,0,4,4,8,12,16,20,28,36,48,64,84,108,140,184,240};
__device__ const int CJ_NB[24] = {1,1,1,1,2,2,3,3,4,4,5,6,7,9,12,15,19,25,31,41,53,65,54,40};

__device__ __forceinline__ int phys4(int g) {
    return (g & ~15) | ((g >> 1) & 7) | ((g & 1) << 3);
}

__global__ __launch_bounds__(128) void conv_kernel(
    const float* __restrict__ syn_e, const float* __restrict__ syn_i,
    const float* __restrict__ basis,
    const float* __restrict__ W_e, const float* __restrict__ W_i,
    const float* __restrict__ b1, const float* __restrict__ W2,
    float* __restrict__ sub_out)
{
    __shared__ float4 win4[16 + 464];             // 16-granule guard + window
    float4* wbase = win4 + 16;
    float2* win2 = reinterpret_cast<float2*>(wbase);
    const int tid = threadIdx.x;
    const int tile = blockIdx.x, s = blockIdx.y, bz = blockIdx.z;
    const int t0 = tile * 512;

    const float* se = syn_e + ((size_t)bz * 20 + s) * 5000;
    const float* si = syn_i + ((size_t)bz * 20 + s) * 5000;
    for (int l = tid; l < 920; l += 128) {
        int t = t0 - 404 + l;
        float ve = 0.f, vi = 0.f;
        if ((unsigned)t < 5000u) { ve = se[t]; vi = si[t]; }
        int g = l >> 1;
        win2[2 * phys4(g) + (l & 1)] = make_float2(ve, vi);
    }
    __syncthreads();

    float z[16][4];
    #pragma unroll
    for (int h = 0; h < 16; ++h) {
        float bv = b1[s * 16 + h];
        #pragma unroll
        for (int k = 0; k < 4; ++k) z[h][k] = bv;
    }

    const int base = 4 * tid + 400;

    for (int j = 0; j < 24; ++j) {
        const float4* bj4 = reinterpret_cast<const float4*>(basis + j * BSTRIDE);
        const int lo = CJ_LO[j];
        const int nb = CJ_NB[j];
        const int co = lo >> 2;
        float be0 = 0.f, be1 = 0.f, be2 = 0.f, be3 = 0.f;
        float bi0 = 0.f, bi1 = 0.f, bi2 = 0.f, bi3 = 0.f;

        auto body = [&](const float4& V0, const float4& V1,
                        const float4& V2, const float4& V3, const float4& c) {
            be0 = fmaf(c.x, V2.x, be0); bi0 = fmaf(c.x, V2.y, bi0);
            be1 = fmaf(c.x, V2.z, be1); bi1 = fmaf(c.x, V2.w, bi1);
            be2 = fmaf(c.x, V3.x, be2); bi2 = fmaf(c.x, V3.y, bi2);
            be3 = fmaf(c.x, V3.z, be3); bi3 = fmaf(c.x, V3.w, bi3);
            be0 = fmaf(c.y, V1.z, be0); bi0 = fmaf(c.y, V1.w, bi0);
            be1 = fmaf(c.y, V2.x, be1); bi1 = fmaf(c.y, V2.y, bi1);
            be2 = fmaf(c.y, V2.z, be2); bi2 = fmaf(c.y, V2.w, bi2);
            be3 = fmaf(c.y, V3.x, be3); bi3 = fmaf(c.y, V3.y, bi3);
            be0 = fmaf(c.z, V1.x, be0); bi0 = fmaf(c.z, V1.y, bi0);
            be1 = fmaf(c.z, V1.z, be1); bi1 = fmaf(c.z, V1.w, bi1);
            be2 = fmaf(c.z, V2.x, be2); bi2 = fmaf(c.z, V2.y, bi2);
            be3 = fmaf(c.z, V2.z, be3); bi3 = fmaf(c.z, V2.w, bi3);
            be0 = fmaf(c.w, V0.z, be0); bi0 = fmaf(c.w, V0.w, bi0);
            be1 = fmaf(c.w, V1.x, be1); bi1 = fmaf(c.w, V1.y, bi1);
            be2 = fmaf(c.w, V1.z, be2); bi2 = fmaf(c.w, V1.w, bi2);
            be3 = fmaf(c.w, V2.x, be3); bi3 = fmaf(c.w, V2.y, bi3);
        };

        const int g0 = (base - lo) >> 1;          // even
        auto LP = [&](int n, float4& lo4, float4& hi4) {
            int p = phys4(g0 - 2 * n);
            lo4 = wbase[p]; hi4 = wbase[p + 8];
        };

        float4 A0, A1, B0, B1, C0, C1, D0, D1;
        float4 E0, E1, F0, F1, G0, G1, H0, H1;
        LP(-1, A0, A1); LP(0, B0, B1); LP(1, C0, C1); LP(2, D0, D1);
        float4 cB = bj4[co], cC = bj4[co + 1], cD = bj4[co + 2];

        int bb = 0;
        while (bb + 8 <= nb) {
            LP(bb + 3, E0, E1); float4 cE = bj4[co + bb + 3];
            body(B0, B1, A0, A1, cB);
            LP(bb + 4, F0, F1); float4 cF = bj4[co + bb + 4];
            body(C0, C1, B0, B1, cC);
            LP(bb + 5, G0, G1); float4 cG = bj4[co + bb + 5];
            body(D0, D1, C0, C1, cD);
            LP(bb + 6, H0, H1); float4 cH = bj4[co + bb + 6];
            body(E0, E1, D0, D1, cE);
            LP(bb + 7, A0, A1); float4 cI = bj4[co + bb + 7];
            body(F0, F1, E0, E1, cF);
            LP(bb + 8, B0, B1); cB = bj4[co + bb + 8];
            body(G0, G1, F0, F1, cG);
            LP(bb + 9, C0, C1); cC = bj4[co + bb + 9];
            body(H0, H1, G0, G1, cH);
            LP(bb + 10, D0, D1); cD = bj4[co + bb + 10];
            body(A0, A1, H0, H1, cI);
            bb += 8;
        }
        int r = nb - bb;
        if (r > 0) { body(B0, B1, A0, A1, cB);
          if (r > 1) { body(C0, C1, B0, B1, cC);
            if (r > 2) { body(D0, D1, C0, C1, cD);
              if (r > 3) { LP(bb + 3, E0, E1); float4 cE = bj4[co + bb + 3];
                body(E0, E1, D0, D1, cE);
                if (r > 4) { LP(bb + 4, F0, F1); float4 cF = bj4[co + bb + 4];
                  body(F0, F1, E0, E1, cF);
                  if (r > 5) { LP(bb + 5, G0, G1); float4 cG = bj4[co + bb + 5];
                    body(G0, G1, F0, F1, cG);
                    if (r > 6) { LP(bb + 6, H0, H1); float4 cH = bj4[co + bb + 6];
                      body(H0, H1, G0, G1, cH); } } } } } } }

        #pragma unroll
        for (int h = 0; h < 16; ++h) {
            float we = W_e[(s * 16 + h) * 24 + j];
            float wi = W_i[(s * 16 + h) * 24 + j];
            z[h][0] = fmaf(we, be0, fmaf(wi, bi0, z[h][0]));
            z[h][1] = fmaf(we, be1, fmaf(wi, bi1, z[h][1]));
            z[h][2] = fmaf(we, be2, fmaf(wi, bi2, z[h][2]));
            z[h][3] = fmaf(we, be3, fmaf(wi, bi3, z[h][3]));
        }
    }

    float w2v[16];
    #pragma unroll
    for (int h = 0; h < 16; ++h) w2v[h] = __expf(W2[s * 16 + h]);

    #pragma unroll
    for (int k = 0; k < 4; ++k) {
        int t = t0 + 4 * tid + k;
        if (t < 5000) {
            float acc = 0.f;
            #pragma unroll
            for (int h = 0; h < 16; ++h) {
                float e2 = __expf(2.0f * z[h][k]);
                float th = 1.0f - 2.0f / (e2 + 1.0f);
                acc = fmaf(w2v[h], th, acc);
            }
            sub_out[((size_t)bz * 5000 + t) * 20 + s] = acc;
        }
    }
}

// ---------------------------------------------------------------------------
// final[b,t] = V_o + sum_s sub_out[b,t,s]
// ---------------------------------------------------------------------------
__global__ __launch_bounds__(256) void final_kernel(
    const float* __restrict__ sub_out, const float* __restrict__ V_o,
    float* __restrict__ fin)
{
    int r = blockIdx.x * 256 + threadIdx.x;
    if (r < 40000) {
        const float* p = sub_out + (size_t)r * 20;
        float a = V_o[0];
        #pragma unroll
        for (int s = 0; s < 20; ++s) a += p[s];
        fin[r] = a;
    }
}

extern "C" void kernel_launch(void* const* d_in, const int* in_sizes, int n_in,
                              void* d_out, int out_size, void* d_ws, size_t ws_size,
                              hipStream_t stream)
{
    const float* S_e     = (const float*)d_in[0];
    const float* S_i     = (const float*)d_in[1];
    const float* E_scale = (const float*)d_in[2];
    const float* I_scale = (const float*)d_in[3];
    const float* W_e     = (const float*)d_in[4];
    const float* W_i     = (const float*)d_in[5];
    const float* W2      = (const float*)d_in[6];
    const float* b1      = (const float*)d_in[7];
    const float* Ce_raw  = (const float*)d_in[8];
    const float* Ci_raw  = (const float*)d_in[9];
    const float* V_o     = (const float*)d_in[10];
    const float* temp    = (const float*)d_in[11];

    float* out     = (float*)d_out;
    float* fin     = out;              // 40000
    float* sub_out = out + 40000;      // 800000
    float* outCe   = out + 840000;     // 40000
    float* outCi   = out + 880000;     // 4000

    float* ws    = (float*)d_ws;
    float* CsT_e = ws;                 // 2048*20 = 40960 (zero-padded)
    float* CsT_i = ws + 40960;         // 256*20  = 5120  (zero-padded)
    float* basis = ws + 46080;         // 24*404  = 9696
    float* syn_e = ws + 55776;         // 800000
    float* syn_i = ws + 855776;        // 800000

    prep_kernel<<<47, 256, 0, stream>>>(Ce_raw, Ci_raw, E_scale, I_scale, temp,
                                        CsT_e, CsT_i, basis, outCe, outCi);
    syn_kernel<16><<<625, 256, 0, stream>>>(S_e, CsT_e, syn_e, 2000);
    syn_kernel<2><<<625, 256, 0, stream>>>(S_i, CsT_i, syn_i, 200);
    conv_kernel<<<dim3(10, 20, 8), 128, 0, stream>>>(syn_e, syn_i, basis,
                                                     W_e, W_i, b1, W2, sub_out);
    final_kernel<<<157, 256, 0, stream>>>(sub_out, V_o, fin);
}